// Round 5
// baseline (1150.527 us; speedup 1.0000x reference)
//
#include <hip/hip_runtime.h>
#include <hip/hip_fp16.h>

// DR2FWL2 conv, MI355X. mlp(e[idx]) == mlp(e)[idx] restructuring; MFMA bf16 hi/lo MLPs.
// R4/R5: atomic-free segment sums via device-built CSR (hist -> scan -> scatter of
// (ia,ib) payload). Hot segcsr kernel is dst-major: thread=(dst,channel-pair) walks
// its triangle list, fp32 register accumulation, one RMW of e (two classes fused)
// + one plain store of mB. R5 fix: phase-2 class binding (B slot MUST be m212 - the
// buffer that gets the inverse-permute add; R4 had m222/m212 transposed).

typedef unsigned short u16;
typedef unsigned int u32;
typedef _Float16 f16;
typedef __attribute__((ext_vector_type(8))) short s16x8;
typedef __attribute__((ext_vector_type(4))) float f32x4;

#define MFMA16(a, b, c) __builtin_amdgcn_mfma_f32_16x16x32_bf16((a), (b), (c), 0, 0, 0)

static __device__ __forceinline__ u16 bf16_rne(float x) {
  u32 u = __float_as_uint(x);
  return (u16)((u + 0x7fffu + ((u >> 16) & 1u)) >> 16);
}
static __device__ __forceinline__ float bf16_f32(u16 h) {
  return __uint_as_float(((u32)h) << 16);
}
static __device__ __forceinline__ void cvt_hilo8(const f32x4 a, const f32x4 b, s16x8& hi, s16x8& lo) {
#pragma unroll
  for (int j = 0; j < 4; j++) {
    float x = a[j];
    u16 h = bf16_rne(x);
    u16 l = bf16_rne(x - bf16_f32(h));
    hi[j] = (short)h; lo[j] = (short)l;
  }
#pragma unroll
  for (int j = 0; j < 4; j++) {
    float x = b[j];
    u16 h = bf16_rne(x);
    u16 l = bf16_rne(x - bf16_f32(h));
    hi[4 + j] = (short)h; lo[4 + j] = (short)l;
  }
}

// ---- CSR build ------------------------------------------------------------
// class c -> (D = dst idx array, A/B = gather idx arrays), all length T
static __device__ __forceinline__ void class_ptrs(int c, const int* t111, const int* t112,
                                                  const int* t122, const int* t222, int T,
                                                  const int*& D, const int*& A, const int*& B) {
  switch (c) {
    case 0: D = t111;          A = t111 + T; B = t111 + 2 * T; break;  // m111
    case 1: D = t112;          A = t112 + T; B = t112 + 2 * T; break;  // m112
    case 2: D = t122;          A = t122 + T; B = t122 + 2 * T; break;  // m122
    case 3: D = t112 + 2 * T;  A = t112;     B = t112 + T;     break;  // m211
    case 4: D = t122 + T;      A = t122;     B = t122 + 2 * T; break;  // m212
    default: D = t222;         A = t222 + T; B = t222 + 2 * T; break;  // m222
  }
}

__global__ __launch_bounds__(256) void hist_kernel(int* __restrict__ pos,
                                                   const int* t111, const int* t112,
                                                   const int* t122, const int* t222, int T, int Emax) {
  int i = blockIdx.x * 256 + threadIdx.x;
  if (i >= 6 * T) return;
  int c = i / T, t = i - c * T;
  const int *D, *A, *B;
  class_ptrs(c, t111, t112, t122, t222, T, D, A, B);
  atomicAdd(&pos[(size_t)c * Emax + D[t]], 1);
}

// per-chunk sums (1024-elem chunks)
__global__ __launch_bounds__(1024) void scanA_kernel(const int* __restrict__ pos, int* __restrict__ partial,
                                                     int Emax, int E1, int E2, int NCH) {
  __shared__ int sh[1024];
  int c = blockIdx.x / NCH, ch = blockIdx.x % NCH;
  int idx = ch * 1024 + threadIdx.x;
  int Ec = c < 3 ? E1 : E2;
  int v = (idx < Ec) ? pos[(size_t)c * Emax + idx] : 0;
  sh[threadIdx.x] = v;
  __syncthreads();
  for (int s = 512; s > 0; s >>= 1) {
    if (threadIdx.x < s) sh[threadIdx.x] += sh[threadIdx.x + s];
    __syncthreads();
  }
  if (threadIdx.x == 0) partial[blockIdx.x] = sh[0];
}

// exclusive scan of partials, per class (single block)
__global__ __launch_bounds__(1024) void scanB_kernel(int* __restrict__ partial, int NCH) {
  __shared__ int sh[1024];
  for (int c = 0; c < 6; c++) {
    int v = (threadIdx.x < NCH) ? partial[c * NCH + threadIdx.x] : 0;
    sh[threadIdx.x] = v;
    __syncthreads();
    for (int off = 1; off < 1024; off <<= 1) {
      int x = (threadIdx.x >= off) ? sh[threadIdx.x - off] : 0;
      __syncthreads();
      sh[threadIdx.x] += x;
      __syncthreads();
    }
    if (threadIdx.x < NCH) partial[c * NCH + threadIdx.x] = sh[threadIdx.x] - v;  // exclusive
    __syncthreads();
  }
}

// final offsets: rp (rowptr, E+1) and pos (running cursor for scatter)
__global__ __launch_bounds__(1024) void scanC_kernel(int* __restrict__ pos, int* __restrict__ rp,
                                                     const int* __restrict__ partial,
                                                     int Emax, int E1, int E2, int NCH, int T) {
  __shared__ int sh[1024];
  int c = blockIdx.x / NCH, ch = blockIdx.x % NCH;
  int idx = ch * 1024 + threadIdx.x;
  int Ec = c < 3 ? E1 : E2;
  int v = (idx < Ec) ? pos[(size_t)c * Emax + idx] : 0;
  sh[threadIdx.x] = v;
  __syncthreads();
  for (int off = 1; off < 1024; off <<= 1) {
    int x = (threadIdx.x >= off) ? sh[threadIdx.x - off] : 0;
    __syncthreads();
    sh[threadIdx.x] += x;
    __syncthreads();
  }
  int excl = sh[threadIdx.x] - v;
  int base = partial[blockIdx.x];
  if (idx < Ec) {
    int off = base + excl;
    rp[(size_t)c * (Emax + 1) + idx] = off;
    pos[(size_t)c * Emax + idx] = off;
    if (idx == Ec - 1) rp[(size_t)c * (Emax + 1) + Ec] = off + v;  // == T
  }
}

typedef struct { int x, y; } i2;

__global__ __launch_bounds__(256) void scatter_kernel(int* __restrict__ pos, i2* __restrict__ payload,
                                                      const int* t111, const int* t112,
                                                      const int* t122, const int* t222, int T, int Emax) {
  int i = blockIdx.x * 256 + threadIdx.x;
  if (i >= 6 * T) return;
  int c = i / T, t = i - c * T;
  const int *D, *A, *B;
  class_ptrs(c, t111, t112, t122, t222, T, D, A, B);
  int slot = atomicAdd(&pos[(size_t)c * Emax + D[t]], 1);
  i2 p; p.x = A[t]; p.y = B[t];
  payload[(size_t)c * T + slot] = p;
}

// ---- hot seg kernel: dst-major, register accumulation, no atomics ---------
// e[r] += sum_A pa*pb + sum_C pa*pb ;  mB[r] = sum_B pa*pb
__global__ __launch_bounds__(256) void segcsr_kernel(
    float2* __restrict__ e, float2* __restrict__ mB,
    const int* __restrict__ rpA, const i2* __restrict__ plA, const __half2* __restrict__ paA, const __half2* __restrict__ pbA,
    const int* __restrict__ rpB, const i2* __restrict__ plB, const __half2* __restrict__ paB, const __half2* __restrict__ pbB,
    const int* __restrict__ rpC, const i2* __restrict__ plC, const __half2* __restrict__ paC, const __half2* __restrict__ pbC,
    int E) {
  int i = blockIdx.x * 256 + threadIdx.x;
  if (i >= E * 32) return;
  int r = i >> 5, cp = i & 31;
  float2 acc = e[(size_t)r * 32 + cp];
  int b0 = rpA[r], b1 = rpA[r + 1];
  for (int t = b0; t < b1; t++) {
    i2 ab = plA[t];
    float2 a = __half22float2(paA[(size_t)ab.x * 32 + cp]);
    float2 b = __half22float2(pbA[(size_t)ab.y * 32 + cp]);
    acc.x += a.x * b.x; acc.y += a.y * b.y;
  }
  b0 = rpC[r]; b1 = rpC[r + 1];
  for (int t = b0; t < b1; t++) {
    i2 ab = plC[t];
    float2 a = __half22float2(paC[(size_t)ab.x * 32 + cp]);
    float2 b = __half22float2(pbC[(size_t)ab.y * 32 + cp]);
    acc.x += a.x * b.x; acc.y += a.y * b.y;
  }
  e[(size_t)r * 32 + cp] = acc;
  float2 accB = make_float2(0.0f, 0.0f);
  b0 = rpB[r]; b1 = rpB[r + 1];
  for (int t = b0; t < b1; t++) {
    i2 ab = plB[t];
    float2 a = __half22float2(paB[(size_t)ab.x * 32 + cp]);
    float2 b = __half22float2(pbB[(size_t)ab.y * 32 + cp]);
    accB.x += a.x * b.x; accB.y += a.y * b.y;
  }
  mB[(size_t)r * 32 + cp] = accB;
}

// ---- misc elementwise ------------------------------------------------------
__global__ __launch_bounds__(256) void repack_split_kernel(const float* __restrict__ src,
                                                           u16* __restrict__ hi, u16* __restrict__ lo, int nmat) {
  int o = blockIdx.x * 256 + threadIdx.x;
  int stride = gridDim.x * 256;
  int total = nmat * 4096;
  for (; o < total; o += stride) {
    int m = o >> 12, r = o & 4095;
    int j = r & 7, lane = (r >> 3) & 63, nt = (r >> 9) & 3, kt = (r >> 11) & 1;
    int k = kt * 32 + ((lane >> 4) << 3) + j;
    int n = nt * 16 + (lane & 15);
    float x = src[(size_t)m * 4096 + k * 64 + n];
    u16 h = bf16_rne(x);
    hi[o] = h;
    lo[o] = bf16_rne(x - bf16_f32(h));
  }
}

__global__ __launch_bounds__(256) void copy_kernel(const float* __restrict__ src, float* __restrict__ dst, int n4) {
  int i = blockIdx.x * 256 + threadIdx.x;
  int stride = gridDim.x * 256;
  const f32x4* s4 = (const f32x4*)src;
  f32x4* d4 = (f32x4*)dst;
  for (; i < n4; i += stride) d4[i] = s4[i];
}

__global__ __launch_bounds__(256) void relu_kernel(float* __restrict__ e, int n4) {
  int i = blockIdx.x * 256 + threadIdx.x;
  int stride = gridDim.x * 256;
  f32x4* e4 = (f32x4*)e;
  for (; i < n4; i += stride) {
    f32x4 v = e4[i];
#pragma unroll
    for (int j = 0; j < 4; j++) v[j] = fmaxf(v[j], 0.0f);
    e4[i] = v;
  }
}

// e[r] += B[r] + B[inv[r]]  (+ optional relu); B is fp32
template <bool DO_RELU>
__global__ __launch_bounds__(256) void addinv_kernel(float* __restrict__ e, const float* __restrict__ B,
                                                     const int* __restrict__ inv, int E) {
  int i = blockIdx.x * 256 + threadIdx.x;
  int stride = gridDim.x * 256;
  int total = E * 16;
  f32x4* e4 = (f32x4*)e;
  const f32x4* B4 = (const f32x4*)B;
  for (; i < total; i += stride) {
    int r = i >> 4, q = i & 15;
    int ir = inv[r];
    f32x4 v = e4[i];
    f32x4 b = B4[i];
    f32x4 bi = B4[(size_t)ir * 16 + q];
#pragma unroll
    for (int j = 0; j < 4; j++) {
      float x = v[j] + b[j] + bi[j];
      v[j] = DO_RELU ? fmaxf(x, 0.0f) : x;
    }
    e4[i] = v;
  }
}

// ---- MLP / linear ----------------------------------------------------------
__global__ __launch_bounds__(256) void mlp4_kernel(
    const float* __restrict__ srcA, const float* __restrict__ srcB,
    f16* __restrict__ d0, f16* __restrict__ d1, f16* __restrict__ d2, f16* __restrict__ d3,
    const u16* __restrict__ w1h_, const u16* __restrict__ w1l_,
    const u16* __restrict__ w2h_, const u16* __restrict__ w2l_,
    const float* __restrict__ b1_, const float* __restrict__ b2_, int s1, int s2) {
  __shared__ float hshm[4][1024];
  const int tid = threadIdx.x;
  const int wave = tid >> 6, lane = tid & 63;
  const int lrow = lane & 15, lk = lane >> 4;
  const int gw = (blockIdx.x * 256 + tid) >> 6;
  const int total = 2 * s1 + 2 * s2;
  if (gw >= total) return;

  int mi, strip;
  const float* src;
  f16* dst;
  if (gw < s1) { mi = 0; strip = gw; src = srcA; dst = d0; }
  else if (gw < 2 * s1) { mi = 1; strip = gw - s1; src = srcA; dst = d1; }
  else if (gw < 2 * s1 + s2) { mi = 2; strip = gw - 2 * s1; src = srcB; dst = d2; }
  else { mi = 3; strip = gw - 2 * s1 - s2; src = srcB; dst = d3; }

  const s16x8* W1H = (const s16x8*)(w1h_ + (size_t)mi * 4096);
  const s16x8* W1L = (const s16x8*)(w1l_ + (size_t)mi * 4096);
  const s16x8* W2H = (const s16x8*)(w2h_ + (size_t)mi * 4096);
  const s16x8* W2L = (const s16x8*)(w2l_ + (size_t)mi * 4096);
  s16x8 w1h[2][4], w1l[2][4], w2h[2][4], w2l[2][4];
#pragma unroll
  for (int kt = 0; kt < 2; kt++)
#pragma unroll
    for (int nt = 0; nt < 4; nt++) {
      const int f = (kt * 4 + nt) * 64 + lane;
      w1h[kt][nt] = W1H[f];
      w1l[kt][nt] = W1L[f];
      w2h[kt][nt] = W2H[f];
      w2l[kt][nt] = W2L[f];
    }
  float bias1[4], bias2[4];
#pragma unroll
  for (int nt = 0; nt < 4; nt++) {
    bias1[nt] = b1_[mi * 64 + nt * 16 + lrow];
    bias2[nt] = b2_[mi * 64 + nt * 16 + lrow];
  }

  float* hl = hshm[wave];
  const float* xp = src + (size_t)(strip * 16 + lrow) * 64 + lk * 8;
  f32x4 x0 = *(const f32x4*)(xp + 0);
  f32x4 x1 = *(const f32x4*)(xp + 4);
  f32x4 x2 = *(const f32x4*)(xp + 32);
  f32x4 x3 = *(const f32x4*)(xp + 36);
  s16x8 ah[2], al[2];
  cvt_hilo8(x0, x1, ah[0], al[0]);
  cvt_hilo8(x2, x3, ah[1], al[1]);

  f32x4 acc[4];
#pragma unroll
  for (int nt = 0; nt < 4; nt++) { acc[nt][0] = bias1[nt]; acc[nt][1] = bias1[nt]; acc[nt][2] = bias1[nt]; acc[nt][3] = bias1[nt]; }
#pragma unroll
  for (int kt = 0; kt < 2; kt++)
#pragma unroll
    for (int nt = 0; nt < 4; nt++) {
      acc[nt] = MFMA16(ah[kt], w1h[kt][nt], acc[nt]);
      acc[nt] = MFMA16(ah[kt], w1l[kt][nt], acc[nt]);
      acc[nt] = MFMA16(al[kt], w1h[kt][nt], acc[nt]);
    }

#pragma unroll
  for (int nt = 0; nt < 4; nt++)
#pragma unroll
    for (int r = 0; r < 4; r++) {
      const int row = lk * 4 + r;
      const int col = nt * 16 + lrow;
      hl[row * 64 + (col ^ ((row & 7) << 2))] = fmaxf(acc[nt][r], 0.0f);
    }
  s16x8 bh[2], bl[2];
#pragma unroll
  for (int kt = 0; kt < 2; kt++) {
    const int colb = kt * 32 + lk * 8;
    const int xr = (lrow & 7) << 2;
    f32x4 h0 = *(const f32x4*)&hl[lrow * 64 + ((colb + 0) ^ xr)];
    f32x4 h1 = *(const f32x4*)&hl[lrow * 64 + ((colb + 4) ^ xr)];
    cvt_hilo8(h0, h1, bh[kt], bl[kt]);
  }

  f32x4 out[4];
#pragma unroll
  for (int nt = 0; nt < 4; nt++) { out[nt][0] = bias2[nt]; out[nt][1] = bias2[nt]; out[nt][2] = bias2[nt]; out[nt][3] = bias2[nt]; }
#pragma unroll
  for (int kt = 0; kt < 2; kt++)
#pragma unroll
    for (int nt = 0; nt < 4; nt++) {
      out[nt] = MFMA16(bh[kt], w2h[kt][nt], out[nt]);
      out[nt] = MFMA16(bh[kt], w2l[kt][nt], out[nt]);
      out[nt] = MFMA16(bl[kt], w2h[kt][nt], out[nt]);
    }

  f16* dp = dst + (size_t)strip * 1024;
#pragma unroll
  for (int nt = 0; nt < 4; nt++)
#pragma unroll
    for (int r = 0; r < 4; r++)
      dp[(lk * 4 + r) * 64 + nt * 16 + lrow] = (f16)out[nt][r];
}

__global__ __launch_bounds__(256) void lin_kernel(const float* __restrict__ src, float* __restrict__ dst,
                                                  const u16* __restrict__ wh_, const u16* __restrict__ wl_,
                                                  const float* __restrict__ b_, int nstrips) {
  const int tid = threadIdx.x;
  const int wave = tid >> 6, lane = tid & 63;
  const int lrow = lane & 15, lk = lane >> 4;

  const s16x8* WH = (const s16x8*)wh_;
  const s16x8* WL = (const s16x8*)wl_;
  s16x8 wh[2][4], wl[2][4];
#pragma unroll
  for (int kt = 0; kt < 2; kt++)
#pragma unroll
    for (int nt = 0; nt < 4; nt++) {
      const int f = (kt * 4 + nt) * 64 + lane;
      wh[kt][nt] = WH[f];
      wl[kt][nt] = WL[f];
    }
  float bias[4];
#pragma unroll
  for (int nt = 0; nt < 4; nt++) bias[nt] = b_[nt * 16 + lrow];

  for (int s = blockIdx.x * 4 + wave; s < nstrips; s += gridDim.x * 4) {
    const float* xp = src + (size_t)(s * 16 + lrow) * 64 + lk * 8;
    f32x4 x0 = *(const f32x4*)(xp + 0);
    f32x4 x1 = *(const f32x4*)(xp + 4);
    f32x4 x2 = *(const f32x4*)(xp + 32);
    f32x4 x3 = *(const f32x4*)(xp + 36);
    s16x8 ah[2], al[2];
    cvt_hilo8(x0, x1, ah[0], al[0]);
    cvt_hilo8(x2, x3, ah[1], al[1]);

    f32x4 acc[4];
#pragma unroll
    for (int nt = 0; nt < 4; nt++) { acc[nt][0] = bias[nt]; acc[nt][1] = bias[nt]; acc[nt][2] = bias[nt]; acc[nt][3] = bias[nt]; }
#pragma unroll
    for (int kt = 0; kt < 2; kt++)
#pragma unroll
      for (int nt = 0; nt < 4; nt++) {
        acc[nt] = MFMA16(ah[kt], wh[kt][nt], acc[nt]);
        acc[nt] = MFMA16(ah[kt], wl[kt][nt], acc[nt]);
        acc[nt] = MFMA16(al[kt], wh[kt][nt], acc[nt]);
      }
    float* dp = dst + (size_t)s * 1024;
#pragma unroll
    for (int nt = 0; nt < 4; nt++)
#pragma unroll
      for (int r = 0; r < 4; r++)
        dp[(lk * 4 + r) * 64 + nt * 16 + lrow] = acc[nt][r];
  }
}

extern "C" void kernel_launch(void* const* d_in, const int* in_sizes, int n_in,
                              void* d_out, int out_size, void* d_ws, size_t ws_size,
                              hipStream_t stream) {
  const float* in_e1 = (const float*)d_in[0];
  const float* in_e2 = (const float*)d_in[1];
  const int* t111 = (const int*)d_in[2];
  const int* t112 = (const int*)d_in[3];
  const int* t122 = (const int*)d_in[4];
  const int* t222 = (const int*)d_in[5];
  const int* inv1 = (const int*)d_in[6];
  const int* inv2 = (const int*)d_in[7];
  const float* mw1 = (const float*)d_in[8];
  const float* mb1 = (const float*)d_in[9];
  const float* mw2 = (const float*)d_in[10];
  const float* mb2 = (const float*)d_in[11];
  const float* lw1 = (const float*)d_in[12];
  const float* lb1 = (const float*)d_in[13];
  const float* lw2 = (const float*)d_in[14];
  const float* lb2 = (const float*)d_in[15];

  const int E1 = in_sizes[0] / 64, E2 = in_sizes[1] / 64;
  const int T = in_sizes[2] / 3;
  const int L = in_sizes[8] / (8 * 64 * 64);
  const int Emax = E1 > E2 ? E1 : E2;
  const size_t nE1 = (size_t)E1 * 64, nE2 = (size_t)E2 * 64;
  const size_t nMax = (size_t)Emax * 64;
  const int NCH = (Emax + 1023) / 1024;

  // workspace layout (8B-aligned chain)
  float* e1b = (float*)d_ws;
  float* e2b = e1b + nE1;
  float* mB = e2b + nE2;
  i2* payload = (i2*)(mB + nMax);          // 6*T pairs
  f16* p0 = (f16*)(payload + (size_t)6 * T);
  f16* p1 = p0 + nE1;
  const size_t wmat = (size_t)L * 8 * 4096;
  u16* w1h = (u16*)(p1 + nE1);
  u16* w1l = w1h + wmat;
  u16* w2h = w1l + wmat;
  u16* w2l = w2h + wmat;
  u16* lwh = w2l + wmat;  // 2 matrices
  u16* lwl = lwh + 8192;
  int* rp = (int*)(lwl + 8192);            // 6*(Emax+1)
  int* pos = rp + (size_t)6 * (Emax + 1);  // 6*Emax
  int* partial = pos + (size_t)6 * Emax;   // 6*NCH
  const size_t needB = (char*)(partial + (size_t)6 * NCH) - (char*)d_ws + 64;
  if (ws_size < needB) return;

  // p2/p3 (fp16) live in d_out; dead before the final linears write it
  f16* p2 = (f16*)d_out;
  f16* p3 = p2 + nE2;

  const int s1 = E1 / 16, s2 = E2 / 16;
  const int mlp4B = (2 * s1 + 2 * s2 + 3) / 4;
  const int ELTB = 2048;
  const int histB = (6 * T + 255) / 256;
  const int segB1 = (E1 * 32 + 255) / 256, segB2 = (E2 * 32 + 255) / 256;

  // ---- CSR build (once per launch; index arrays are fixed inputs) ----
  hipMemsetAsync(pos, 0, (size_t)6 * Emax * 4, stream);
  hist_kernel<<<histB, 256, 0, stream>>>(pos, t111, t112, t122, t222, T, Emax);
  scanA_kernel<<<6 * NCH, 1024, 0, stream>>>(pos, partial, Emax, E1, E2, NCH);
  scanB_kernel<<<1, 1024, 0, stream>>>(partial, NCH);
  scanC_kernel<<<6 * NCH, 1024, 0, stream>>>(pos, rp, partial, Emax, E1, E2, NCH, T);
  scatter_kernel<<<histB, 256, 0, stream>>>(pos, payload, t111, t112, t122, t222, T, Emax);

  // ---- weights & state ----
  repack_split_kernel<<<256, 256, 0, stream>>>(mw1, w1h, w1l, L * 8);
  repack_split_kernel<<<256, 256, 0, stream>>>(mw2, w2h, w2l, L * 8);
  repack_split_kernel<<<32, 256, 0, stream>>>(lw1, lwh, lwl, 1);
  repack_split_kernel<<<32, 256, 0, stream>>>(lw2, lwh + 4096, lwl + 4096, 1);
  copy_kernel<<<ELTB, 256, 0, stream>>>(in_e1, e1b, (int)(nE1 / 4));
  copy_kernel<<<ELTB, 256, 0, stream>>>(in_e2, e2b, (int)(nE2 / 4));

  const int EP1 = Emax + 1;
  for (int li = 0; li < L; li++) {
    const size_t mo = (size_t)li * 8 * 4096;
    const size_t bo = (size_t)li * 8 * 64;
    // phase 1: e1 update. p0=mlp0(e1) p1=mlp1(e1) p2=mlp2(e2) p3=mlp3(e2)
    mlp4_kernel<<<mlp4B, 256, 0, stream>>>(e1b, e2b, p0, p1, p2, p3,
                                           w1h + mo, w1l + mo, w2h + mo, w2l + mo,
                                           mb1 + bo, mb2 + bo, s1, s2);
    // A: m111 -> e1, B: m112 -> mB (gets inv-add), C: m122 -> e1
    segcsr_kernel<<<segB1, 256, 0, stream>>>(
        (float2*)e1b, (float2*)mB,
        rp + 0 * EP1, payload + (size_t)0 * T, (const __half2*)p0, (const __half2*)p0,
        rp + 1 * EP1, payload + (size_t)1 * T, (const __half2*)p1, (const __half2*)p2,
        rp + 2 * EP1, payload + (size_t)2 * T, (const __half2*)p3, (const __half2*)p3, E1);
    addinv_kernel<false><<<ELTB, 256, 0, stream>>>(e1b, mB, inv1, E1);

    // phase 2: e2 update (NEW e1 pre-relu, OLD e2). p0=mlp4(e1) p1=mlp5(e1) p2=mlp6(e2) p3=mlp7(e2)
    mlp4_kernel<<<mlp4B, 256, 0, stream>>>(e1b, e2b, p0, p1, p2, p3,
                                           w1h + mo + 4 * 4096, w1l + mo + 4 * 4096,
                                           w2h + mo + 4 * 4096, w2l + mo + 4 * 4096,
                                           mb1 + bo + 4 * 64, mb2 + bo + 4 * 64, s1, s2);
    // A: m211 (class 3) -> e2, B: m212 (class 4) -> mB (gets inv-add), C: m222 (class 5) -> e2
    // R5 FIX: B slot must be class 4 (m212), C slot class 5 (m222). R4 had these transposed.
    segcsr_kernel<<<segB2, 256, 0, stream>>>(
        (float2*)e2b, (float2*)mB,
        rp + 3 * EP1, payload + (size_t)3 * T, (const __half2*)p0, (const __half2*)p0,
        rp + 4 * EP1, payload + (size_t)4 * T, (const __half2*)p1, (const __half2*)p2,
        rp + 5 * EP1, payload + (size_t)5 * T, (const __half2*)p3, (const __half2*)p3, E2);
    addinv_kernel<true><<<ELTB, 256, 0, stream>>>(e2b, mB, inv2, E2);  // + relu(e2)

    relu_kernel<<<ELTB, 256, 0, stream>>>(e1b, (int)(nE1 / 4));
  }

  lin_kernel<<<(s1 + 3) / 4, 256, 0, stream>>>(e1b, (float*)d_out, lwh, lwl, lb1, s1);
  lin_kernel<<<(s2 + 3) / 4, 256, 0, stream>>>(e2b, (float*)d_out + nE1, lwh + 4096, lwl + 4096, lb2, s2);
}

// Round 6
// 896.067 us; speedup vs baseline: 1.2840x; 1.2840x over previous
//
#include <hip/hip_runtime.h>
#include <hip/hip_fp16.h>

// DR2FWL2 conv, MI355X. mlp(e[idx]) == mlp(e)[idx] restructuring; MFMA bf16 hi/lo MLPs.
// R6: revert seg to R3's triangle-major packed-fp16 atomics (CSR was net-negative:
// build cost ~220us, pull no faster than the 280G atomic-op/s push floor).
// New: mlpN grid-stride kernel (BPU blocks/unit, ~9 strips/wave) amortizes the 32KB
// weight-fragment L2 reads ~12x (R3 re-read them per strip); 6+2 MLP schedule;
// last-layer relu(e1) fused into lin<RELU>; q4/q5 alias q0/q1.

typedef unsigned short u16;
typedef unsigned int u32;
typedef _Float16 f16;
typedef __attribute__((ext_vector_type(8))) short s16x8;
typedef __attribute__((ext_vector_type(4))) float f32x4;
typedef __attribute__((ext_vector_type(4))) _Float16 f16x4;

#define MFMA16(a, b, c) __builtin_amdgcn_mfma_f32_16x16x32_bf16((a), (b), (c), 0, 0, 0)

static __device__ __forceinline__ u16 bf16_rne(float x) {
  u32 u = __float_as_uint(x);
  return (u16)((u + 0x7fffu + ((u >> 16) & 1u)) >> 16);
}
static __device__ __forceinline__ float bf16_f32(u16 h) {
  return __uint_as_float(((u32)h) << 16);
}
static __device__ __forceinline__ void cvt_hilo8(const f32x4 a, const f32x4 b, s16x8& hi, s16x8& lo) {
#pragma unroll
  for (int j = 0; j < 4; j++) {
    float x = a[j];
    u16 h = bf16_rne(x);
    u16 l = bf16_rne(x - bf16_f32(h));
    hi[j] = (short)h; lo[j] = (short)l;
  }
#pragma unroll
  for (int j = 0; j < 4; j++) {
    float x = b[j];
    u16 h = bf16_rne(x);
    u16 l = bf16_rne(x - bf16_f32(h));
    hi[4 + j] = (short)h; lo[4 + j] = (short)l;
  }
}

// Repack fp32 [64][64] (k-major) weights into MFMA-fragment-ordered bf16 hi/lo.
__global__ __launch_bounds__(256) void repack_split_kernel(const float* __restrict__ src,
                                                           u16* __restrict__ hi, u16* __restrict__ lo, int nmat) {
  int o = blockIdx.x * 256 + threadIdx.x;
  int stride = gridDim.x * 256;
  int total = nmat * 4096;
  for (; o < total; o += stride) {
    int m = o >> 12, r = o & 4095;
    int j = r & 7, lane = (r >> 3) & 63, nt = (r >> 9) & 3, kt = (r >> 11) & 1;
    int k = kt * 32 + ((lane >> 4) << 3) + j;
    int n = nt * 16 + (lane & 15);
    float x = src[(size_t)m * 4096 + k * 64 + n];
    u16 h = bf16_rne(x);
    hi[o] = h;
    lo[o] = bf16_rne(x - bf16_f32(h));
  }
}

__global__ __launch_bounds__(256) void copy_kernel(const float* __restrict__ src, float* __restrict__ dst, int n4) {
  int i = blockIdx.x * 256 + threadIdx.x;
  int stride = gridDim.x * 256;
  const f32x4* s4 = (const f32x4*)src;
  f32x4* d4 = (f32x4*)dst;
  for (; i < n4; i += stride) d4[i] = s4[i];
}

__global__ __launch_bounds__(256) void relu_kernel(float* __restrict__ e, int n4) {
  int i = blockIdx.x * 256 + threadIdx.x;
  int stride = gridDim.x * 256;
  f32x4* e4 = (f32x4*)e;
  for (; i < n4; i += stride) {
    f32x4 v = e4[i];
#pragma unroll
    for (int j = 0; j < 4; j++) v[j] = fmaxf(v[j], 0.0f);
    e4[i] = v;
  }
}

// e[r] += A[r] + B[r] + B[inv[r]]  (+ optional relu); A,B fp16
template <bool DO_RELU>
__global__ __launch_bounds__(256) void addinv2_kernel(float* __restrict__ e, const f16* __restrict__ A,
                                                      const f16* __restrict__ B, const int* __restrict__ inv, int E) {
  int i = blockIdx.x * 256 + threadIdx.x;
  int stride = gridDim.x * 256;
  int total = E * 16;
  f32x4* e4 = (f32x4*)e;
  const f16x4* A4 = (const f16x4*)A;
  const f16x4* B4 = (const f16x4*)B;
  for (; i < total; i += stride) {
    int r = i >> 4, q = i & 15;
    int ir = inv[r];
    f32x4 v = e4[i];
    f16x4 a = A4[i];
    f16x4 b = B4[i];
    f16x4 bi = B4[(size_t)ir * 16 + q];
#pragma unroll
    for (int j = 0; j < 4; j++) {
      float x = v[j] + (float)a[j] + (float)b[j] + (float)bi[j];
      v[j] = DO_RELU ? fmaxf(x, 0.0f) : x;
    }
    e4[i] = v;
  }
}

// Three fused segment-sums with packed-fp16 atomics (R3-proven, the 280G op/s path).
// seg X: dst[iX0[t]] += paX[iX1[t]] * pbX[iX2[t]]   (A,B,C -> dstA, dstB, dstA)
__global__ __launch_bounds__(256) void seg3_kernel(
    __half2* __restrict__ dstA, __half2* __restrict__ dstB,
    const __half2* __restrict__ paA, const __half2* __restrict__ pbA,
    const int* __restrict__ iA0, const int* __restrict__ iA1, const int* __restrict__ iA2,
    const __half2* __restrict__ paB, const __half2* __restrict__ pbB,
    const int* __restrict__ iB0, const int* __restrict__ iB1, const int* __restrict__ iB2,
    const __half2* __restrict__ paC, const __half2* __restrict__ pbC,
    const int* __restrict__ iC0, const int* __restrict__ iC1, const int* __restrict__ iC2,
    int T) {
  int i = blockIdx.x * 256 + threadIdx.x;
  int stride = gridDim.x * 256;
  int total = 3 * T * 32;
  for (; i < total; i += stride) {
    int u = i >> 5, cp = i & 31;
    __half2* dst;
    const __half2 *pa, *pb;
    const int *i0, *i1, *i2;
    int t;
    if (u < T) { t = u; dst = dstA; pa = paA; pb = pbA; i0 = iA0; i1 = iA1; i2 = iA2; }
    else if (u < 2 * T) { t = u - T; dst = dstB; pa = paB; pb = pbB; i0 = iB0; i1 = iB1; i2 = iB2; }
    else { t = u - 2 * T; dst = dstA; pa = paC; pb = pbC; i0 = iC0; i1 = iC1; i2 = iC2; }
    __half2 va = pa[(size_t)i1[t] * 32 + cp];
    __half2 vb = pb[(size_t)i2[t] * 32 + cp];
    float2 fa = __half22float2(va), fb = __half22float2(vb);
    __half2 prod = __floats2half2_rn(fa.x * fb.x, fa.y * fb.y);
    unsafeAtomicAdd(&dst[(size_t)i0[t] * 32 + cp], prod);
  }
}

// Multi-unit fused 2-layer MLP, grid-stride: unit = blockIdx/BPU, wave strides strips.
// Weight fragments loaded ONCE per wave (the R3 version re-read them per strip).
// Per-strip body verbatim from the proven mlp4.
__global__ __launch_bounds__(256) void mlpN_kernel(
    const float* __restrict__ e1s, const float* __restrict__ e2s,
    f16* __restrict__ d0, f16* __restrict__ d1, f16* __restrict__ d2,
    f16* __restrict__ d3, f16* __restrict__ d4, f16* __restrict__ d5,
    const u16* __restrict__ w1h_, const u16* __restrict__ w1l_,
    const u16* __restrict__ w2h_, const u16* __restrict__ w2l_,
    const float* __restrict__ b1_, const float* __restrict__ b2_,
    int miPacked, int selMask, int nUnits, int s1, int s2, int BPU) {
  __shared__ float hshm[4][1024];
  const int u = blockIdx.x / BPU;
  if (u >= nUnits) return;
  const int tid = threadIdx.x;
  const int wave = tid >> 6, lane = tid & 63;
  const int lrow = lane & 15, lk = lane >> 4;

  const int mi = (miPacked >> (4 * u)) & 15;
  const int sel = (selMask >> u) & 1;
  const float* src = sel ? e2s : e1s;
  const int strips = sel ? s2 : s1;
  f16* dst = (u == 0) ? d0 : (u == 1) ? d1 : (u == 2) ? d2 : (u == 3) ? d3 : (u == 4) ? d4 : d5;

  const s16x8* W1H = (const s16x8*)(w1h_ + (size_t)mi * 4096);
  const s16x8* W1L = (const s16x8*)(w1l_ + (size_t)mi * 4096);
  const s16x8* W2H = (const s16x8*)(w2h_ + (size_t)mi * 4096);
  const s16x8* W2L = (const s16x8*)(w2l_ + (size_t)mi * 4096);
  s16x8 w1h[2][4], w1l[2][4], w2h[2][4], w2l[2][4];
#pragma unroll
  for (int kt = 0; kt < 2; kt++)
#pragma unroll
    for (int nt = 0; nt < 4; nt++) {
      const int f = (kt * 4 + nt) * 64 + lane;
      w1h[kt][nt] = W1H[f];
      w1l[kt][nt] = W1L[f];
      w2h[kt][nt] = W2H[f];
      w2l[kt][nt] = W2L[f];
    }
  float bias1[4], bias2[4];
#pragma unroll
  for (int nt = 0; nt < 4; nt++) {
    bias1[nt] = b1_[mi * 64 + nt * 16 + lrow];
    bias2[nt] = b2_[mi * 64 + nt * 16 + lrow];
  }

  float* hl = hshm[wave];
  const int lb = blockIdx.x % BPU;
  for (int strip = lb * 4 + wave; strip < strips; strip += BPU * 4) {
    const float* xp = src + (size_t)(strip * 16 + lrow) * 64 + lk * 8;
    f32x4 x0 = *(const f32x4*)(xp + 0);
    f32x4 x1 = *(const f32x4*)(xp + 4);
    f32x4 x2 = *(const f32x4*)(xp + 32);
    f32x4 x3 = *(const f32x4*)(xp + 36);
    s16x8 ah[2], al[2];
    cvt_hilo8(x0, x1, ah[0], al[0]);
    cvt_hilo8(x2, x3, ah[1], al[1]);

    f32x4 acc[4];
#pragma unroll
    for (int nt = 0; nt < 4; nt++) { acc[nt][0] = bias1[nt]; acc[nt][1] = bias1[nt]; acc[nt][2] = bias1[nt]; acc[nt][3] = bias1[nt]; }
#pragma unroll
    for (int kt = 0; kt < 2; kt++)
#pragma unroll
      for (int nt = 0; nt < 4; nt++) {
        acc[nt] = MFMA16(ah[kt], w1h[kt][nt], acc[nt]);
        acc[nt] = MFMA16(ah[kt], w1l[kt][nt], acc[nt]);
        acc[nt] = MFMA16(al[kt], w1h[kt][nt], acc[nt]);
      }

    // relu + transpose through per-wave LDS tile (XOR swizzle, conflict-free; wave-private)
#pragma unroll
    for (int nt = 0; nt < 4; nt++)
#pragma unroll
      for (int r = 0; r < 4; r++) {
        const int row = lk * 4 + r;
        const int col = nt * 16 + lrow;
        hl[row * 64 + (col ^ ((row & 7) << 2))] = fmaxf(acc[nt][r], 0.0f);
      }
    s16x8 bh[2], bl[2];
#pragma unroll
    for (int kt = 0; kt < 2; kt++) {
      const int colb = kt * 32 + lk * 8;
      const int xr = (lrow & 7) << 2;
      f32x4 h0 = *(const f32x4*)&hl[lrow * 64 + ((colb + 0) ^ xr)];
      f32x4 h1 = *(const f32x4*)&hl[lrow * 64 + ((colb + 4) ^ xr)];
      cvt_hilo8(h0, h1, bh[kt], bl[kt]);
    }

    f32x4 out[4];
#pragma unroll
    for (int nt = 0; nt < 4; nt++) { out[nt][0] = bias2[nt]; out[nt][1] = bias2[nt]; out[nt][2] = bias2[nt]; out[nt][3] = bias2[nt]; }
#pragma unroll
    for (int kt = 0; kt < 2; kt++)
#pragma unroll
      for (int nt = 0; nt < 4; nt++) {
        out[nt] = MFMA16(bh[kt], w2h[kt][nt], out[nt]);
        out[nt] = MFMA16(bh[kt], w2l[kt][nt], out[nt]);
        out[nt] = MFMA16(bl[kt], w2h[kt][nt], out[nt]);
      }

    f16* dp = dst + (size_t)strip * 1024;
#pragma unroll
    for (int nt = 0; nt < 4; nt++)
#pragma unroll
      for (int r = 0; r < 4; r++)
        dp[(lk * 4 + r) * 64 + nt * 16 + lrow] = (f16)out[nt][r];
  }
}

// Single linear: dst = (RELU? relu(src):src) @ W + b (fp32 in/out); grid-stride.
template <bool RELU>
__global__ __launch_bounds__(256) void lin_kernel(const float* __restrict__ src, float* __restrict__ dst,
                                                  const u16* __restrict__ wh_, const u16* __restrict__ wl_,
                                                  const float* __restrict__ b_, int nstrips) {
  const int tid = threadIdx.x;
  const int wave = tid >> 6, lane = tid & 63;
  const int lrow = lane & 15, lk = lane >> 4;

  const s16x8* WH = (const s16x8*)wh_;
  const s16x8* WL = (const s16x8*)wl_;
  s16x8 wh[2][4], wl[2][4];
#pragma unroll
  for (int kt = 0; kt < 2; kt++)
#pragma unroll
    for (int nt = 0; nt < 4; nt++) {
      const int f = (kt * 4 + nt) * 64 + lane;
      wh[kt][nt] = WH[f];
      wl[kt][nt] = WL[f];
    }
  float bias[4];
#pragma unroll
  for (int nt = 0; nt < 4; nt++) bias[nt] = b_[nt * 16 + lrow];

  for (int s = blockIdx.x * 4 + wave; s < nstrips; s += gridDim.x * 4) {
    const float* xp = src + (size_t)(s * 16 + lrow) * 64 + lk * 8;
    f32x4 x0 = *(const f32x4*)(xp + 0);
    f32x4 x1 = *(const f32x4*)(xp + 4);
    f32x4 x2 = *(const f32x4*)(xp + 32);
    f32x4 x3 = *(const f32x4*)(xp + 36);
    if (RELU) {
#pragma unroll
      for (int j = 0; j < 4; j++) {
        x0[j] = fmaxf(x0[j], 0.0f); x1[j] = fmaxf(x1[j], 0.0f);
        x2[j] = fmaxf(x2[j], 0.0f); x3[j] = fmaxf(x3[j], 0.0f);
      }
    }
    s16x8 ah[2], al[2];
    cvt_hilo8(x0, x1, ah[0], al[0]);
    cvt_hilo8(x2, x3, ah[1], al[1]);

    f32x4 acc[4];
#pragma unroll
    for (int nt = 0; nt < 4; nt++) { acc[nt][0] = bias[nt]; acc[nt][1] = bias[nt]; acc[nt][2] = bias[nt]; acc[nt][3] = bias[nt]; }
#pragma unroll
    for (int kt = 0; kt < 2; kt++)
#pragma unroll
      for (int nt = 0; nt < 4; nt++) {
        acc[nt] = MFMA16(ah[kt], wh[kt][nt], acc[nt]);
        acc[nt] = MFMA16(ah[kt], wl[kt][nt], acc[nt]);
        acc[nt] = MFMA16(al[kt], wh[kt][nt], acc[nt]);
      }
    float* dp = dst + (size_t)s * 1024;
#pragma unroll
    for (int nt = 0; nt < 4; nt++)
#pragma unroll
      for (int r = 0; r < 4; r++)
        dp[(lk * 4 + r) * 64 + nt * 16 + lrow] = acc[nt][r];
  }
}

extern "C" void kernel_launch(void* const* d_in, const int* in_sizes, int n_in,
                              void* d_out, int out_size, void* d_ws, size_t ws_size,
                              hipStream_t stream) {
  const float* in_e1 = (const float*)d_in[0];
  const float* in_e2 = (const float*)d_in[1];
  const int* t111 = (const int*)d_in[2];
  const int* t112 = (const int*)d_in[3];
  const int* t122 = (const int*)d_in[4];
  const int* t222 = (const int*)d_in[5];
  const int* inv1 = (const int*)d_in[6];
  const int* inv2 = (const int*)d_in[7];
  const float* mw1 = (const float*)d_in[8];
  const float* mb1 = (const float*)d_in[9];
  const float* mw2 = (const float*)d_in[10];
  const float* mb2 = (const float*)d_in[11];
  const float* lw1 = (const float*)d_in[12];
  const float* lb1 = (const float*)d_in[13];
  const float* lw2 = (const float*)d_in[14];
  const float* lb2 = (const float*)d_in[15];

  const int E1 = in_sizes[0] / 64, E2 = in_sizes[1] / 64;
  const int T = in_sizes[2] / 3;
  const int L = in_sizes[8] / (8 * 64 * 64);
  const size_t nE1 = (size_t)E1 * 64, nE2 = (size_t)E2 * 64;
  const size_t nMax = nE1 > nE2 ? nE1 : nE2;

  // ws: e1b,e2b fp32 | mA,mB fp16 (adjacent, one memset) | q0,q1 fp16 (q4,q5 alias)
  float* e1b = (float*)d_ws;
  float* e2b = e1b + nE1;
  f16* mA = (f16*)(e2b + nE2);
  f16* mB = mA + nMax;
  f16* q0 = mB + nMax;
  f16* q1 = q0 + nE1;
  const size_t wmat = (size_t)L * 8 * 4096;
  u16* w1h = (u16*)(q1 + nE1);
  u16* w1l = w1h + wmat;
  u16* w2h = w1l + wmat;
  u16* w2l = w2h + wmat;
  u16* lwh = w2l + wmat;  // 2 matrices
  u16* lwl = lwh + 8192;
  const size_t needB = (nE1 + nE2) * 4 + (2 * nMax + 2 * nE1) * 2 + (4 * wmat + 4 * 4096) * 2 + 64;
  if (ws_size < needB) return;

  // q2,q3,q6,q7 (fp16, E2-sized) live in d_out (exactly fills it); dead before lins write
  f16* q2 = (f16*)d_out;
  f16* q3 = q2 + nE2;
  f16* q6 = q3 + nE2;
  f16* q7 = q6 + nE2;
  f16* q4 = q0;  // alias: q0/q1 dead after phase-1 seg
  f16* q5 = q1;

  const int s1 = E1 / 16, s2 = E2 / 16;
  const int SEGB = 2048, ELTB = 2048, BPU = 256, LINB = 256;

  repack_split_kernel<<<256, 256, 0, stream>>>(mw1, w1h, w1l, L * 8);
  repack_split_kernel<<<256, 256, 0, stream>>>(mw2, w2h, w2l, L * 8);
  repack_split_kernel<<<32, 256, 0, stream>>>(lw1, lwh, lwl, 1);
  repack_split_kernel<<<32, 256, 0, stream>>>(lw2, lwh + 4096, lwl + 4096, 1);
  copy_kernel<<<ELTB, 256, 0, stream>>>(in_e1, e1b, (int)(nE1 / 4));
  copy_kernel<<<ELTB, 256, 0, stream>>>(in_e2, e2b, (int)(nE2 / 4));

  for (int li = 0; li < L; li++) {
    const u16* W1H = w1h + (size_t)li * 8 * 4096;
    const u16* W1L = w1l + (size_t)li * 8 * 4096;
    const u16* W2H = w2h + (size_t)li * 8 * 4096;
    const u16* W2L = w2l + (size_t)li * 8 * 4096;
    const float* B1 = mb1 + (size_t)li * 8 * 64;
    const float* B2 = mb2 + (size_t)li * 8 * 64;

    // M6: q0=mlp0(e1) q1=mlp1(e1) q2=mlp2(e2) q3=mlp3(e2) q6=mlp6(e2) q7=mlp7(e2)
    mlpN_kernel<<<6 * BPU, 256, 0, stream>>>(e1b, e2b, q0, q1, q2, q3, q6, q7,
                                             W1H, W1L, W2H, W2L, B1, B2,
                                             0x763210, 0x3C, 6, s1, s2, BPU);
    hipMemsetAsync(mA, 0, 2 * nMax * 2, stream);  // clears mA and mB
    // phase 1: A=m111 (q0*q0 -> mA), B=m112 (q1*q2 -> mB, gets inv-add), C=m122 (q3*q3 -> mA)
    seg3_kernel<<<SEGB, 256, 0, stream>>>(
        (__half2*)mA, (__half2*)mB,
        (const __half2*)q0, (const __half2*)q0, t111, t111 + T, t111 + 2 * T,
        (const __half2*)q1, (const __half2*)q2, t112, t112 + T, t112 + 2 * T,
        (const __half2*)q3, (const __half2*)q3, t122, t122 + T, t122 + 2 * T, T);
    addinv2_kernel<false><<<ELTB, 256, 0, stream>>>(e1b, mA, mB, inv1, E1);

    // M2: q4=mlp4(e1_new) q5=mlp5(e1_new)  (e1 pre-relu, per reference)
    mlpN_kernel<<<2 * BPU, 256, 0, stream>>>(e1b, e2b, q4, q5, q2, q3, q6, q7,
                                             W1H, W1L, W2H, W2L, B1, B2,
                                             0x54, 0x0, 2, s1, s2, BPU);
    if (li < L - 1) relu_kernel<<<ELTB, 256, 0, stream>>>(e1b, (int)(nE1 / 4));

    hipMemsetAsync(mA, 0, 2 * nMax * 2, stream);
    // phase 2: A=m211 (q4*q4 -> mA), B=m212 (q5*q6 -> mB, gets inv-add), C=m222 (q7*q7 -> mA)
    seg3_kernel<<<SEGB, 256, 0, stream>>>(
        (__half2*)mA, (__half2*)mB,
        (const __half2*)q4, (const __half2*)q4, t112 + 2 * T, t112, t112 + T,
        (const __half2*)q5, (const __half2*)q6, t122 + T, t122, t122 + 2 * T,
        (const __half2*)q7, (const __half2*)q7, t222, t222 + T, t222 + 2 * T, T);
    addinv2_kernel<true><<<ELTB, 256, 0, stream>>>(e2b, mA, mB, inv2, E2);  // + relu(e2)
  }

  // final linears (e1b is pre-relu: fuse relu into the load; e2b already relu'd)
  lin_kernel<true><<<LINB, 256, 0, stream>>>(e1b, (float*)d_out, lwh, lwl, lb1, s1);
  lin_kernel<false><<<LINB, 256, 0, stream>>>(e2b, (float*)d_out + nE1, lwh + 4096, lwl + 4096, lb2, s2);
}

// Round 7
// 818.641 us; speedup vs baseline: 1.4054x; 1.0946x over previous
//
#include <hip/hip_runtime.h>
#include <hip/hip_fp16.h>

// DR2FWL2 conv, MI355X. mlp(e[idx]) == mlp(e)[idx] restructuring; MFMA bf16 hi/lo MLPs.
// R7: fp16 e-state. m111/m122 (m211/m222) atomics land DIRECTLY in e1b/e2b (mA buffer,
// its memsets, and its addinv reads eliminated). fp16->bf16 hi/lo split is EXACT, so
// MLP accuracy unchanged; every e-pass halves its bytes. seg3 stays at the ~290G
// atomic-dword/s fabric ceiling (~131us x4) - that floor is untouched this round.

typedef unsigned short u16;
typedef unsigned int u32;
typedef _Float16 f16;
typedef __attribute__((ext_vector_type(8))) short s16x8;
typedef __attribute__((ext_vector_type(4))) float f32x4;
typedef __attribute__((ext_vector_type(8))) _Float16 f16x8;

#define MFMA16(a, b, c) __builtin_amdgcn_mfma_f32_16x16x32_bf16((a), (b), (c), 0, 0, 0)

static __device__ __forceinline__ u16 bf16_rne(float x) {
  u32 u = __float_as_uint(x);
  return (u16)((u + 0x7fffu + ((u >> 16) & 1u)) >> 16);
}
static __device__ __forceinline__ float bf16_f32(u16 h) {
  return __uint_as_float(((u32)h) << 16);
}
// 8 fp16 -> hi/lo bf16 fragments (EXACT: 11-bit mantissa fits in 8+8)
static __device__ __forceinline__ void cvt_hilo8_f16(const f16x8 v, s16x8& hi, s16x8& lo) {
#pragma unroll
  for (int j = 0; j < 8; j++) {
    float x = (float)v[j];
    u16 h = bf16_rne(x);
    hi[j] = (short)h;
    lo[j] = (short)bf16_rne(x - bf16_f32(h));
  }
}

// Repack fp32 [64][64] (k-major) weights into MFMA-fragment-ordered bf16 hi/lo.
__global__ __launch_bounds__(256) void repack_split_kernel(const float* __restrict__ src,
                                                           u16* __restrict__ hi, u16* __restrict__ lo, int nmat) {
  int o = blockIdx.x * 256 + threadIdx.x;
  int stride = gridDim.x * 256;
  int total = nmat * 4096;
  for (; o < total; o += stride) {
    int m = o >> 12, r = o & 4095;
    int j = r & 7, lane = (r >> 3) & 63, nt = (r >> 9) & 3, kt = (r >> 11) & 1;
    int k = kt * 32 + ((lane >> 4) << 3) + j;
    int n = nt * 16 + (lane & 15);
    float x = src[(size_t)m * 4096 + k * 64 + n];
    u16 h = bf16_rne(x);
    hi[o] = h;
    lo[o] = bf16_rne(x - bf16_f32(h));
  }
}

// fp32 -> fp16 state init
__global__ __launch_bounds__(256) void cvtcopy_kernel(const float* __restrict__ src, f16* __restrict__ dst, int n8) {
  int i = blockIdx.x * 256 + threadIdx.x;
  int stride = gridDim.x * 256;
  const f32x4* s4 = (const f32x4*)src;
  f16x8* d8 = (f16x8*)dst;
  for (; i < n8; i += stride) {
    f32x4 a = s4[2 * i], b = s4[2 * i + 1];
    f16x8 o;
#pragma unroll
    for (int j = 0; j < 4; j++) { o[j] = (f16)a[j]; o[4 + j] = (f16)b[j]; }
    d8[i] = o;
  }
}

__global__ __launch_bounds__(256) void relu16_kernel(f16* __restrict__ e, int n8) {
  int i = blockIdx.x * 256 + threadIdx.x;
  int stride = gridDim.x * 256;
  f16x8* e8 = (f16x8*)e;
  for (; i < n8; i += stride) {
    f16x8 v = e8[i];
#pragma unroll
    for (int j = 0; j < 8; j++) v[j] = v[j] > (f16)0 ? v[j] : (f16)0;
    e8[i] = v;
  }
}

// e[r] += B[r] + B[inv[r]]  (+ optional relu); e,B fp16
template <bool DO_RELU>
__global__ __launch_bounds__(256) void addinvB_kernel(f16* __restrict__ e, const f16* __restrict__ B,
                                                      const int* __restrict__ inv, int E) {
  int i = blockIdx.x * 256 + threadIdx.x;
  int stride = gridDim.x * 256;
  int total = E * 8;
  f16x8* e8 = (f16x8*)e;
  const f16x8* B8 = (const f16x8*)B;
  for (; i < total; i += stride) {
    int r = i >> 3, q = i & 7;
    int ir = inv[r];
    f16x8 ev = e8[i];
    f16x8 bv = B8[i];
    f16x8 biv = B8[(size_t)ir * 8 + q];
#pragma unroll
    for (int j = 0; j < 8; j++) {
      float x = (float)ev[j] + (float)bv[j] + (float)biv[j];
      ev[j] = (f16)(DO_RELU ? fmaxf(x, 0.0f) : x);
    }
    e8[i] = ev;
  }
}

// Three fused segment-sums, packed-fp16 atomics (~290G dword/s fabric ceiling).
// A,C classes -> dstA (the e-state itself); B class -> dstB (mB, gets inv-add later).
__global__ __launch_bounds__(256) void seg3_kernel(
    __half2* __restrict__ dstA, __half2* __restrict__ dstB,
    const __half2* __restrict__ paA, const __half2* __restrict__ pbA,
    const int* __restrict__ iA0, const int* __restrict__ iA1, const int* __restrict__ iA2,
    const __half2* __restrict__ paB, const __half2* __restrict__ pbB,
    const int* __restrict__ iB0, const int* __restrict__ iB1, const int* __restrict__ iB2,
    const __half2* __restrict__ paC, const __half2* __restrict__ pbC,
    const int* __restrict__ iC0, const int* __restrict__ iC1, const int* __restrict__ iC2,
    int T) {
  int i = blockIdx.x * 256 + threadIdx.x;
  int stride = gridDim.x * 256;
  int total = 3 * T * 32;
  for (; i < total; i += stride) {
    int u = i >> 5, cp = i & 31;
    __half2* dst;
    const __half2 *pa, *pb;
    const int *i0, *i1, *i2;
    int t;
    if (u < T) { t = u; dst = dstA; pa = paA; pb = pbA; i0 = iA0; i1 = iA1; i2 = iA2; }
    else if (u < 2 * T) { t = u - T; dst = dstB; pa = paB; pb = pbB; i0 = iB0; i1 = iB1; i2 = iB2; }
    else { t = u - 2 * T; dst = dstA; pa = paC; pb = pbC; i0 = iC0; i1 = iC1; i2 = iC2; }
    __half2 va = pa[(size_t)i1[t] * 32 + cp];
    __half2 vb = pb[(size_t)i2[t] * 32 + cp];
    float2 fa = __half22float2(va), fb = __half22float2(vb);
    __half2 prod = __floats2half2_rn(fa.x * fb.x, fa.y * fb.y);
    unsafeAtomicAdd(&dst[(size_t)i0[t] * 32 + cp], prod);
  }
}

// Multi-unit fused 2-layer MLP, grid-stride; fp16 input state, fp16 output.
// Weight fragments (fragment-ordered, one 16B load each) resident per wave.
__global__ __launch_bounds__(256) void mlpN_kernel(
    const f16* __restrict__ e1s, const f16* __restrict__ e2s,
    f16* __restrict__ d0, f16* __restrict__ d1, f16* __restrict__ d2,
    f16* __restrict__ d3, f16* __restrict__ d4, f16* __restrict__ d5,
    const u16* __restrict__ w1h_, const u16* __restrict__ w1l_,
    const u16* __restrict__ w2h_, const u16* __restrict__ w2l_,
    const float* __restrict__ b1_, const float* __restrict__ b2_,
    int miPacked, int selMask, int nUnits, int s1, int s2, int BPU) {
  __shared__ float hshm[4][1024];
  const int u = blockIdx.x / BPU;
  if (u >= nUnits) return;
  const int tid = threadIdx.x;
  const int wave = tid >> 6, lane = tid & 63;
  const int lrow = lane & 15, lk = lane >> 4;

  const int mi = (miPacked >> (4 * u)) & 15;
  const int sel = (selMask >> u) & 1;
  const f16* src = sel ? e2s : e1s;
  const int strips = sel ? s2 : s1;
  f16* dst = (u == 0) ? d0 : (u == 1) ? d1 : (u == 2) ? d2 : (u == 3) ? d3 : (u == 4) ? d4 : d5;

  const s16x8* W1H = (const s16x8*)(w1h_ + (size_t)mi * 4096);
  const s16x8* W1L = (const s16x8*)(w1l_ + (size_t)mi * 4096);
  const s16x8* W2H = (const s16x8*)(w2h_ + (size_t)mi * 4096);
  const s16x8* W2L = (const s16x8*)(w2l_ + (size_t)mi * 4096);
  s16x8 w1h[2][4], w1l[2][4], w2h[2][4], w2l[2][4];
#pragma unroll
  for (int kt = 0; kt < 2; kt++)
#pragma unroll
    for (int nt = 0; nt < 4; nt++) {
      const int f = (kt * 4 + nt) * 64 + lane;
      w1h[kt][nt] = W1H[f];
      w1l[kt][nt] = W1L[f];
      w2h[kt][nt] = W2H[f];
      w2l[kt][nt] = W2L[f];
    }
  float bias1[4], bias2[4];
#pragma unroll
  for (int nt = 0; nt < 4; nt++) {
    bias1[nt] = b1_[mi * 64 + nt * 16 + lrow];
    bias2[nt] = b2_[mi * 64 + nt * 16 + lrow];
  }

  float* hl = hshm[wave];
  const int lb = blockIdx.x % BPU;
  for (int strip = lb * 4 + wave; strip < strips; strip += BPU * 4) {
    const f16* xp = src + (size_t)(strip * 16 + lrow) * 64 + lk * 8;
    f16x8 xa = *(const f16x8*)(xp);       // k-tile 0
    f16x8 xb = *(const f16x8*)(xp + 32);  // k-tile 1
    s16x8 ah[2], al[2];
    cvt_hilo8_f16(xa, ah[0], al[0]);
    cvt_hilo8_f16(xb, ah[1], al[1]);

    f32x4 acc[4];
#pragma unroll
    for (int nt = 0; nt < 4; nt++) { acc[nt][0] = bias1[nt]; acc[nt][1] = bias1[nt]; acc[nt][2] = bias1[nt]; acc[nt][3] = bias1[nt]; }
#pragma unroll
    for (int kt = 0; kt < 2; kt++)
#pragma unroll
      for (int nt = 0; nt < 4; nt++) {
        acc[nt] = MFMA16(ah[kt], w1h[kt][nt], acc[nt]);
        acc[nt] = MFMA16(ah[kt], w1l[kt][nt], acc[nt]);
        acc[nt] = MFMA16(al[kt], w1h[kt][nt], acc[nt]);
      }

    // relu + transpose through per-wave LDS tile (XOR swizzle, conflict-free)
#pragma unroll
    for (int nt = 0; nt < 4; nt++)
#pragma unroll
      for (int r = 0; r < 4; r++) {
        const int row = lk * 4 + r;
        const int col = nt * 16 + lrow;
        hl[row * 64 + (col ^ ((row & 7) << 2))] = fmaxf(acc[nt][r], 0.0f);
      }
    s16x8 bh[2], bl[2];
#pragma unroll
    for (int kt = 0; kt < 2; kt++) {
      const int colb = kt * 32 + lk * 8;
      const int xr = (lrow & 7) << 2;
      f32x4 h0 = *(const f32x4*)&hl[lrow * 64 + ((colb + 0) ^ xr)];
      f32x4 h1 = *(const f32x4*)&hl[lrow * 64 + ((colb + 4) ^ xr)];
      // fp32 -> hi/lo bf16
      s16x8 hi, lo;
#pragma unroll
      for (int j = 0; j < 4; j++) {
        float x = h0[j];
        u16 h = bf16_rne(x);
        hi[j] = (short)h; lo[j] = (short)bf16_rne(x - bf16_f32(h));
      }
#pragma unroll
      for (int j = 0; j < 4; j++) {
        float x = h1[j];
        u16 h = bf16_rne(x);
        hi[4 + j] = (short)h; lo[4 + j] = (short)bf16_rne(x - bf16_f32(h));
      }
      bh[kt] = hi; bl[kt] = lo;
    }

    f32x4 out[4];
#pragma unroll
    for (int nt = 0; nt < 4; nt++) { out[nt][0] = bias2[nt]; out[nt][1] = bias2[nt]; out[nt][2] = bias2[nt]; out[nt][3] = bias2[nt]; }
#pragma unroll
    for (int kt = 0; kt < 2; kt++)
#pragma unroll
      for (int nt = 0; nt < 4; nt++) {
        out[nt] = MFMA16(bh[kt], w2h[kt][nt], out[nt]);
        out[nt] = MFMA16(bh[kt], w2l[kt][nt], out[nt]);
        out[nt] = MFMA16(bl[kt], w2h[kt][nt], out[nt]);
      }

    f16* dp = dst + (size_t)strip * 1024;
#pragma unroll
    for (int nt = 0; nt < 4; nt++)
#pragma unroll
      for (int r = 0; r < 4; r++)
        dp[(lk * 4 + r) * 64 + nt * 16 + lrow] = (f16)out[nt][r];
  }
}

// Single linear: dst = (RELU? relu(src):src) @ W + b ; fp16 in, fp32 out; grid-stride.
template <bool RELU>
__global__ __launch_bounds__(256) void lin_kernel(const f16* __restrict__ src, float* __restrict__ dst,
                                                  const u16* __restrict__ wh_, const u16* __restrict__ wl_,
                                                  const float* __restrict__ b_, int nstrips) {
  const int tid = threadIdx.x;
  const int wave = tid >> 6, lane = tid & 63;
  const int lrow = lane & 15, lk = lane >> 4;

  const s16x8* WH = (const s16x8*)wh_;
  const s16x8* WL = (const s16x8*)wl_;
  s16x8 wh[2][4], wl[2][4];
#pragma unroll
  for (int kt = 0; kt < 2; kt++)
#pragma unroll
    for (int nt = 0; nt < 4; nt++) {
      const int f = (kt * 4 + nt) * 64 + lane;
      wh[kt][nt] = WH[f];
      wl[kt][nt] = WL[f];
    }
  float bias[4];
#pragma unroll
  for (int nt = 0; nt < 4; nt++) bias[nt] = b_[nt * 16 + lrow];

  for (int s = blockIdx.x * 4 + wave; s < nstrips; s += gridDim.x * 4) {
    const f16* xp = src + (size_t)(s * 16 + lrow) * 64 + lk * 8;
    f16x8 xa = *(const f16x8*)(xp);
    f16x8 xb = *(const f16x8*)(xp + 32);
    if (RELU) {
#pragma unroll
      for (int j = 0; j < 8; j++) {
        xa[j] = xa[j] > (f16)0 ? xa[j] : (f16)0;
        xb[j] = xb[j] > (f16)0 ? xb[j] : (f16)0;
      }
    }
    s16x8 ah[2], al[2];
    cvt_hilo8_f16(xa, ah[0], al[0]);
    cvt_hilo8_f16(xb, ah[1], al[1]);

    f32x4 acc[4];
#pragma unroll
    for (int nt = 0; nt < 4; nt++) { acc[nt][0] = bias[nt]; acc[nt][1] = bias[nt]; acc[nt][2] = bias[nt]; acc[nt][3] = bias[nt]; }
#pragma unroll
    for (int kt = 0; kt < 2; kt++)
#pragma unroll
      for (int nt = 0; nt < 4; nt++) {
        acc[nt] = MFMA16(ah[kt], wh[kt][nt], acc[nt]);
        acc[nt] = MFMA16(ah[kt], wl[kt][nt], acc[nt]);
        acc[nt] = MFMA16(al[kt], wh[kt][nt], acc[nt]);
      }
    float* dp = dst + (size_t)s * 1024;
#pragma unroll
    for (int nt = 0; nt < 4; nt++)
#pragma unroll
      for (int r = 0; r < 4; r++)
        dp[(lk * 4 + r) * 64 + nt * 16 + lrow] = acc[nt][r];
  }
}

extern "C" void kernel_launch(void* const* d_in, const int* in_sizes, int n_in,
                              void* d_out, int out_size, void* d_ws, size_t ws_size,
                              hipStream_t stream) {
  const float* in_e1 = (const float*)d_in[0];
  const float* in_e2 = (const float*)d_in[1];
  const int* t111 = (const int*)d_in[2];
  const int* t112 = (const int*)d_in[3];
  const int* t122 = (const int*)d_in[4];
  const int* t222 = (const int*)d_in[5];
  const int* inv1 = (const int*)d_in[6];
  const int* inv2 = (const int*)d_in[7];
  const float* mw1 = (const float*)d_in[8];
  const float* mb1 = (const float*)d_in[9];
  const float* mw2 = (const float*)d_in[10];
  const float* mb2 = (const float*)d_in[11];
  const float* lw1 = (const float*)d_in[12];
  const float* lb1 = (const float*)d_in[13];
  const float* lw2 = (const float*)d_in[14];
  const float* lb2 = (const float*)d_in[15];

  const int E1 = in_sizes[0] / 64, E2 = in_sizes[1] / 64;
  const int T = in_sizes[2] / 3;
  const int L = in_sizes[8] / (8 * 64 * 64);
  const size_t nE1 = (size_t)E1 * 64, nE2 = (size_t)E2 * 64;
  const size_t nMax = nE1 > nE2 ? nE1 : nE2;

  // ws: e1b,e2b,mB,q0,q1 all fp16 | weights bf16 hi/lo (fragment-ordered)
  f16* e1b = (f16*)d_ws;
  f16* e2b = e1b + nE1;
  f16* mB = e2b + nE2;
  f16* q0 = mB + nMax;
  f16* q1 = q0 + nE1;
  const size_t wmat = (size_t)L * 8 * 4096;
  u16* w1h = (u16*)(q1 + nE1);
  u16* w1l = w1h + wmat;
  u16* w2h = w1l + wmat;
  u16* w2l = w2h + wmat;
  u16* lwh = w2l + wmat;  // 2 matrices
  u16* lwl = lwh + 8192;
  const size_t needB = (nE1 + nE2 + nMax + 2 * nE1) * 2 + (4 * wmat + 4 * 4096) * 2 + 64;
  if (ws_size < needB) return;

  // q2,q3,q6,q7 (fp16, E2-sized) live in d_out (exactly fills it); dead before lins write
  f16* q2 = (f16*)d_out;
  f16* q3 = q2 + nE2;
  f16* q6 = q3 + nE2;
  f16* q7 = q6 + nE2;
  f16* q4 = q0;  // alias: q0/q1 dead after phase-1 seg
  f16* q5 = q1;

  const int s1 = E1 / 16, s2 = E2 / 16;
  const int SEGB = 2048, ELTB = 2048, BPU = 256, LINB = 256;

  repack_split_kernel<<<256, 256, 0, stream>>>(mw1, w1h, w1l, L * 8);
  repack_split_kernel<<<256, 256, 0, stream>>>(mw2, w2h, w2l, L * 8);
  repack_split_kernel<<<32, 256, 0, stream>>>(lw1, lwh, lwl, 1);
  repack_split_kernel<<<32, 256, 0, stream>>>(lw2, lwh + 4096, lwl + 4096, 1);
  cvtcopy_kernel<<<ELTB, 256, 0, stream>>>(in_e1, e1b, (int)(nE1 / 8));
  cvtcopy_kernel<<<ELTB, 256, 0, stream>>>(in_e2, e2b, (int)(nE2 / 8));

  for (int li = 0; li < L; li++) {
    const u16* W1H = w1h + (size_t)li * 8 * 4096;
    const u16* W1L = w1l + (size_t)li * 8 * 4096;
    const u16* W2H = w2h + (size_t)li * 8 * 4096;
    const u16* W2L = w2l + (size_t)li * 8 * 4096;
    const float* B1 = mb1 + (size_t)li * 8 * 64;
    const float* B2 = mb2 + (size_t)li * 8 * 64;

    // M6: q0=mlp0(e1) q1=mlp1(e1) q2=mlp2(e2) q3=mlp3(e2) q6=mlp6(e2) q7=mlp7(e2)
    mlpN_kernel<<<6 * BPU, 256, 0, stream>>>(e1b, e2b, q0, q1, q2, q3, q6, q7,
                                             W1H, W1L, W2H, W2L, B1, B2,
                                             0x763210, 0x3C, 6, s1, s2, BPU);
    hipMemsetAsync(mB, 0, nE1 * 2, stream);
    // phase 1: A=m111 (q0*q0 -> e1b direct), B=m112 (q1*q2 -> mB, gets inv-add), C=m122 (q3*q3 -> e1b)
    seg3_kernel<<<SEGB, 256, 0, stream>>>(
        (__half2*)e1b, (__half2*)mB,
        (const __half2*)q0, (const __half2*)q0, t111, t111 + T, t111 + 2 * T,
        (const __half2*)q1, (const __half2*)q2, t112, t112 + T, t112 + 2 * T,
        (const __half2*)q3, (const __half2*)q3, t122, t122 + T, t122 + 2 * T, T);
    addinvB_kernel<false><<<ELTB, 256, 0, stream>>>(e1b, mB, inv1, E1);

    // M2: q4=mlp4(e1_new) q5=mlp5(e1_new)  (e1 pre-relu, per reference)
    mlpN_kernel<<<2 * BPU, 256, 0, stream>>>(e1b, e2b, q4, q5, q2, q3, q6, q7,
                                             W1H, W1L, W2H, W2L, B1, B2,
                                             0x54, 0x0, 2, s1, s2, BPU);
    if (li < L - 1) relu16_kernel<<<ELTB, 256, 0, stream>>>(e1b, (int)(nE1 / 8));

    hipMemsetAsync(mB, 0, nE2 * 2, stream);
    // phase 2: A=m211 (q4*q4 -> e2b direct), B=m212 (q5*q6 -> mB, gets inv-add), C=m222 (q7*q7 -> e2b)
    seg3_kernel<<<SEGB, 256, 0, stream>>>(
        (__half2*)e2b, (__half2*)mB,
        (const __half2*)q4, (const __half2*)q4, t112 + 2 * T, t112, t112 + T,
        (const __half2*)q5, (const __half2*)q6, t122 + T, t122, t122 + 2 * T,
        (const __half2*)q7, (const __half2*)q7, t222, t222 + T, t222 + 2 * T, T);
    addinvB_kernel<true><<<ELTB, 256, 0, stream>>>(e2b, mB, inv2, E2);  // + relu(e2)
  }

  // final linears (e1b pre-relu: fuse relu into load; e2b already relu'd)
  lin_kernel<true><<<LINB, 256, 0, stream>>>(e1b, (float*)d_out, lwh, lwl, lb1, s1);
  lin_kernel<false><<<LINB, 256, 0, stream>>>(e2b, (float*)d_out + nE1, lwh + 4096, lwl + 4096, lb2, s2);
}